// Round 5
// baseline (1054.901 us; speedup 1.0000x reference)
//
#include <hip/hip_runtime.h>

typedef unsigned short u16;
typedef unsigned int u32;
typedef __bf16 bf16x8 __attribute__((ext_vector_type(8)));
typedef float f32x4 __attribute__((ext_vector_type(4)));
typedef u16 u16x4 __attribute__((ext_vector_type(4)));
typedef u16 u16x8 __attribute__((ext_vector_type(8)));
typedef float f4v __attribute__((ext_vector_type(4)));

#define NB   512
#define CCH  256
#define HW   196
#define LROW 40                    // act LDS row stride (elems)
#define ACT_ELEMS (197 * LROW)     // 7880 elems per buffer (incl. halo row)
#define WLDS_ELEMS (9 * 64 * 32)   // 18432 elems
#define SSTR 53248                 // per-sample elems, blocked [c4][208][4]
#define CGSTR 147456               // w3 per-co-group stride: 8cc*9rs*64co*32ci

__device__ inline u16 f2bf(float f) {
    u32 u = __float_as_uint(f);
    u32 r = (u + 0x7FFFu + ((u >> 16) & 1u)) >> 16;
    return (u16)r;
}

// ---------------- weight convert / reorder ----------------
__global__ void wconv_kernel(const float* __restrict__ Wc3, const float* __restrict__ Wt3,
                             const float* __restrict__ Wf3, const float* __restrict__ Wc1,
                             const float* __restrict__ Wt1, const float* __restrict__ Wf1,
                             u16* __restrict__ w3, u16* __restrict__ w1o)
{
    int bid = blockIdx.x, tid = threadIdx.x;
    if (bid < 768) {
        int wset = bid >> 8;
        int co = bid & 255;
        int cgi = co >> 6, cop = co & 63;
        int cc = tid >> 5, cip = tid & 31;
        const float* src = wset == 0 ? Wc3 : (wset == 1 ? Wt3 : Wf3);
#pragma unroll
        for (int rs = 0; rs < 9; ++rs) {
            float v = src[(co * 256 + tid) * 9 + rs];
            w3[wset * 589824 + cgi * CGSTR + (cc * 9 + rs) * 2048 + cop * 32 + cip] = f2bf(v);
        }
    } else {
        int k = (bid - 768) * 256 + tid;
        int wsel = k >> 14;
        int rem = k & 16383;
        const float* src = wsel == 0 ? Wc1 : (wsel == 1 ? Wt1 : Wf1);
        f4v v = *(const f4v*)(src + rem * 4);
        u16x4 o = { f2bf(v.x), f2bf(v.y), f2bf(v.z), f2bf(v.w) };
        *(u16x4*)(w1o + wsel * 65536 + rem * 4) = o;
    }
}

// ---------------- box overlap mask ----------------
__global__ void mask_kernel(const float* __restrict__ boxes, int* __restrict__ counts,
                            int* __restrict__ members)
{
    int i = blockIdx.x;
    int ln = threadIdx.x;
    __shared__ int cnt;
    if (ln == 0) cnt = 0;
    __syncthreads();
    float xi0 = boxes[i * 4 + 0], yi0 = boxes[i * 4 + 1];
    float xi1 = boxes[i * 4 + 2], yi1 = boxes[i * 4 + 3];
    for (int j = ln; j < NB; j += 64) {
        float xj0 = boxes[j * 4 + 0], yj0 = boxes[j * 4 + 1];
        float xj1 = boxes[j * 4 + 2], yj1 = boxes[j * 4 + 3];
        float areaj = (xj1 - xj0) * (yj1 - yj0);
        float lx = fmaxf(xi0, xj0), ly = fmaxf(yi0, yj0);
        float rx = fminf(xi1, xj1), ry = fminf(yi1, yj1);
        float w = fmaxf(rx - lx, 0.f), h = fmaxf(ry - ly, 0.f);
        if (w * h / areaj > 0.9f) {
            int p = atomicAdd(&cnt, 1);
            members[i * NB + p] = j;
        }
    }
    __syncthreads();
    if (ln == 0) counts[i] = cnt;
}

// ---------------- branch input -> blocked bf16 [s][c4][208][4] ----------------
__global__ __launch_bounds__(256) void bin_kernel(
    const float* __restrict__ x, const int* __restrict__ classes,
    const int* __restrict__ counts, const int* __restrict__ members,
    u16* __restrict__ bin)
{
    const int bid = blockIdx.x;
    const int s = bid >> 2;
    const int qtr = bid & 3;
    const int tid = threadIdx.x;
    const int cnt = counts[s];
    u16* binS = bin + s * SSTR;
    __shared__ int mem[NB];
    int lcnt;
    if (classes[s] != 0 || cnt <= 1) {
        if (tid == 0) mem[0] = s;
        lcnt = 1;
    } else {
        for (int u = tid; u < cnt; u += 256) mem[u] = members[s * NB + u];
        lcnt = cnt;
    }
    __syncthreads();
    const float inv = 1.f / (float)lcnt;
    for (int v = tid; v < 784; v += 256) {
        int c4r = v / 49;
        int g = v - c4r * 49;
        int c4 = qtr * 16 + c4r;
        int px0 = g * 4;
        f4v a0 = {0.f, 0.f, 0.f, 0.f}, a1 = a0, a2 = a0, a3 = a0;
        for (int k = 0; k < lcnt; ++k) {
            const float* xm = x + (size_t)(mem[k] * CCH + c4 * 4) * HW + px0;
            a0 += *(const f4v*)(xm);
            a1 += *(const f4v*)(xm + HW);
            a2 += *(const f4v*)(xm + 2 * HW);
            a3 += *(const f4v*)(xm + 3 * HW);
        }
        u16x8 o0, o1;
        o0[0] = f2bf(a0.x * inv); o0[1] = f2bf(a1.x * inv);
        o0[2] = f2bf(a2.x * inv); o0[3] = f2bf(a3.x * inv);
        o0[4] = f2bf(a0.y * inv); o0[5] = f2bf(a1.y * inv);
        o0[6] = f2bf(a2.y * inv); o0[7] = f2bf(a3.y * inv);
        o1[0] = f2bf(a0.z * inv); o1[1] = f2bf(a1.z * inv);
        o1[2] = f2bf(a2.z * inv); o1[3] = f2bf(a3.z * inv);
        o1[4] = f2bf(a0.w * inv); o1[5] = f2bf(a1.w * inv);
        o1[6] = f2bf(a2.w * inv); o1[7] = f2bf(a3.w * inv);
        u16* dst = binS + (c4 * 208 + px0) * 4;
        *(u16x8*)(dst) = o0;
        *(u16x8*)(dst + 8) = o1;
    }
}

// ---------------- conv3x3 v5: R1 structure (LDS weights+acts, 2 barriers/cc)
// + register prefetch: global loads for cc+1 issued right after the compute
// barrier, consumed at the next stage phase. Latency hides under 144 MFMA.
__global__ __launch_bounds__(256, 3) void conv3x3_kernel(
    const u16* __restrict__ in, u16* __restrict__ out,
    const u16* __restrict__ w0, const u16* __restrict__ w1,
    const int* __restrict__ classes, int useClass)
{
    __shared__ u16 lds[ACT_ELEMS + WLDS_ELEMS];   // 52,624 B -> 3 blocks/CU
    const int tid = threadIdx.x;
    const int bid = blockIdx.x;
    const int s  = bid >> 2;
    const int cg = bid & 3;
    const int wv = tid >> 6;
    const int ln = tid & 63;
    const int q = ln >> 4;
    const int l15 = ln & 15;
    const int t0 = (wv == 0) ? 0 : (wv == 1 ? 4 : (wv == 2 ? 7 : 10));
    const int NT = (wv == 0) ? 4 : 3;

    const u16* wsel = (((useClass && classes[s] == 0) ? w1 : w0)) + cg * CGSTR;

    if (tid < 20) ((u32*)lds)[196 * (LROW / 2) + tid] = 0u;   // zero halo row

    int baddr[4], vbits[4];
#pragma unroll
    for (int t = 0; t < 4; ++t) {
        int px = (t0 + t) * 16 + l15;
        int vb = 0;
        int ba = 196 * LROW + q * 8;
        if (t < NT && px < HW) {
            int y = px / 14;
            int x = px - y * 14;
            ba = px * LROW + q * 8;
#pragma unroll
            for (int rs = 0; rs < 9; ++rs) {
                int iy = y + rs / 3 - 1;
                int ix = x + rs % 3 - 1;
                if (iy >= 0 && iy < 14 && ix >= 0 && ix < 14) vb |= 1 << rs;
            }
        }
        baddr[t] = ba;
        vbits[t] = vb;
    }

    f32x4 acc[4][4];
#pragma unroll
    for (int a = 0; a < 4; ++a)
#pragma unroll
        for (int t = 0; t < 4; ++t) acc[a][t] = (f32x4){0.f, 0.f, 0.f, 0.f};

    const u16* inS = in + s * SSTR;

    // per-thread staging items: acts (6 each + 32 threads take a 7th), weights (9 b128)
    int goff[7], loff[7];
#pragma unroll
    for (int j = 0; j < 7; ++j) {
        int v = tid + j * 256;
        if (v > 1567) v = 1567;
        int ci4 = v & 7;
        int px = v >> 3;
        goff[j] = (ci4 * 208 + px) * 4;
        loff[j] = px * LROW + ci4 * 4;
    }
    const int has7 = (tid < 32);

    u16x4 apf[7];
    u16x8 wpf[9];
    // prologue: load cc=0 into regs
    {
#pragma unroll
        for (int j = 0; j < 6; ++j) apf[j] = *(const u16x4*)(inS + goff[j]);
        if (has7) apf[6] = *(const u16x4*)(inS + goff[6]);
#pragma unroll
        for (int k = 0; k < 9; ++k)
            wpf[k] = *(const u16x8*)(wsel + (tid + k * 256) * 8);
    }

    for (int cc = 0; cc < 8; ++cc) {
        __syncthreads();   // compute(cc-1) done reading both regions
        // stage from regs (fast: pure LDS writes, no global latency)
#pragma unroll
        for (int j = 0; j < 6; ++j) *(u16x4*)(lds + loff[j]) = apf[j];
        if (has7) *(u16x4*)(lds + loff[6]) = apf[6];
#pragma unroll
        for (int k = 0; k < 9; ++k)
            *(u16x8*)(lds + ACT_ELEMS + (tid + k * 256) * 8) = wpf[k];
        __syncthreads();
        // issue next-cc loads; latency hidden under the MFMA loop below
        if (cc < 7) {
            const u16* gs = inS + (cc + 1) * (8 * 208 * 4);
#pragma unroll
            for (int j = 0; j < 6; ++j) apf[j] = *(const u16x4*)(gs + goff[j]);
            if (has7) apf[6] = *(const u16x4*)(gs + goff[6]);
            const u16* wcc = wsel + (cc + 1) * WLDS_ELEMS;
#pragma unroll
            for (int k = 0; k < 9; ++k)
                wpf[k] = *(const u16x8*)(wcc + (tid + k * 256) * 8);
        }

#pragma unroll
        for (int rs = 0; rs < 9; ++rs) {
            const int d = (rs / 3 - 1) * 14 + (rs % 3 - 1);
            bf16x8 af[4];
#pragma unroll
            for (int sub = 0; sub < 4; ++sub)
                af[sub] = *(const bf16x8*)(lds + ACT_ELEMS + rs * 2048 + (sub * 16 + l15) * 32 + q * 8);
#pragma unroll
            for (int t = 0; t < 4; ++t) {
                if (t < NT) {
                    int addr = ((vbits[t] >> rs) & 1) ? (baddr[t] + d * LROW)
                                                      : (196 * LROW + q * 8);
                    bf16x8 b = *(const bf16x8*)(lds + addr);
#pragma unroll
                    for (int sub = 0; sub < 4; ++sub)
                        acc[sub][t] = __builtin_amdgcn_mfma_f32_16x16x32_bf16(af[sub], b, acc[sub][t], 0, 0, 0);
                }
            }
        }
    }

#pragma unroll
    for (int sub = 0; sub < 4; ++sub) {
        int co4 = cg * 16 + sub * 4 + q;
#pragma unroll
        for (int t = 0; t < 4; ++t) {
            if (t < NT) {
                int pxs = (t0 + t) * 16 + l15;
                u16x4 o = { f2bf(acc[sub][t][0]), f2bf(acc[sub][t][1]),
                            f2bf(acc[sub][t][2]), f2bf(acc[sub][t][3]) };
                *(u16x4*)(out + (s * (size_t)SSTR) + (co4 * 208 + pxs) * 4) = o;
            }
        }
    }
}

// ---------------- conv1x1 v3: merged-sample (512 thr, 8 waves = 4cg x 2 px-halves)
// Acts staged ONCE per sample (was 4x), double-buffered, ONE barrier per cc,
// act+weight reg-prefetch. Weights from global (L1/L2-resident, as in R1).
template <int MODE>
__global__ __launch_bounds__(512) void conv1x1_kernel(
    const u16* __restrict__ in, const u16* __restrict__ w0, const u16* __restrict__ w1,
    const int* __restrict__ classes, int useClass,
    const float* __restrict__ xin, const float* __restrict__ gcin,
    const float* __restrict__ gamma, const float* __restrict__ beta,
    const float* __restrict__ mean, const float* __restrict__ var,
    void* __restrict__ outv)
{
    __shared__ u16 lds[2 * ACT_ELEMS];            // 31,520 B
    const int tid = threadIdx.x;
    const int s  = blockIdx.x;
    const int wv = tid >> 6;                      // 0..7
    const int ln = tid & 63;
    const int q = ln >> 4;
    const int l15 = ln & 15;
    const int cg  = wv >> 1;
    const int pxh = wv & 1;
    const int t0 = pxh ? 7 : 0;
    const int NT = pxh ? 6 : 7;

    const u16* wsel = (useClass && classes[s] == 0) ? w1 : w0;

    if (tid < 20) {
        ((u32*)lds)[196 * (LROW / 2) + tid] = 0u;
        ((u32*)lds)[(ACT_ELEMS / 2) + 196 * (LROW / 2) + tid] = 0u;
    }

    int baddr[7];
#pragma unroll
    for (int t = 0; t < 7; ++t) {
        int px = (t0 + t) * 16 + l15;
        baddr[t] = (t < NT && px < HW ? px : 196) * LROW + q * 8;
    }

    f32x4 acc[4][7];
#pragma unroll
    for (int a = 0; a < 4; ++a)
#pragma unroll
        for (int t = 0; t < 7; ++t) acc[a][t] = (f32x4){0.f, 0.f, 0.f, 0.f};

    const u16* inS = in + s * (size_t)SSTR;

    // staging items, px-major (coalesced): v = ci4*196 + px, 1568 = 3*512 + 32
    int goff[4], loff[4];
#pragma unroll
    for (int j = 0; j < 4; ++j) {
        int v = tid + j * 512;
        if (v > 1567) v = 1567;
        int ci4 = v / 196;
        int px = v - ci4 * 196;
        goff[j] = (ci4 * 208 + px) * 4;
        loff[j] = px * LROW + ci4 * 4;
    }
    const int has4 = (tid < 32);

    u16x4 apf[4];
    bf16x8 af[4];
    // prologue: stage cc=0 into buf0, load af(cc=0)
    {
#pragma unroll
        for (int j = 0; j < 3; ++j) apf[j] = *(const u16x4*)(inS + goff[j]);
        if (has4) apf[3] = *(const u16x4*)(inS + goff[3]);
#pragma unroll
        for (int j = 0; j < 3; ++j) *(u16x4*)(lds + loff[j]) = apf[j];
        if (has4) *(u16x4*)(lds + loff[3]) = apf[3];
#pragma unroll
        for (int sub = 0; sub < 4; ++sub)
            af[sub] = *(const bf16x8*)(wsel + ((cg * 64 + sub * 16 + l15) * 256 + q * 8));
    }

    for (int cc = 0; cc < 8; ++cc) {
        __syncthreads();   // buf[cc&1] staged; compute(cc-1) done
        // issue next-cc loads (acts + weights) -> regs
        bf16x8 afn[4];
        if (cc < 7) {
            const u16* gs = inS + (cc + 1) * (8 * 208 * 4);
#pragma unroll
            for (int j = 0; j < 3; ++j) apf[j] = *(const u16x4*)(gs + goff[j]);
            if (has4) apf[3] = *(const u16x4*)(gs + goff[3]);
#pragma unroll
            for (int sub = 0; sub < 4; ++sub)
                afn[sub] = *(const bf16x8*)(wsel + ((cg * 64 + sub * 16 + l15) * 256 + (cc + 1) * 32 + q * 8));
        }
        const u16* bb = lds + (cc & 1) * ACT_ELEMS;
#pragma unroll
        for (int t = 0; t < 7; ++t) {
            if (t < NT) {
                bf16x8 b = *(const bf16x8*)(bb + baddr[t]);
#pragma unroll
                for (int sub = 0; sub < 4; ++sub)
                    acc[sub][t] = __builtin_amdgcn_mfma_f32_16x16x32_bf16(af[sub], b, acc[sub][t], 0, 0, 0);
            }
        }
        if (cc < 7) {
            u16* nb = lds + ((cc + 1) & 1) * ACT_ELEMS;
#pragma unroll
            for (int j = 0; j < 3; ++j) *(u16x4*)(nb + loff[j]) = apf[j];
            if (has4) *(u16x4*)(nb + loff[3]) = apf[3];
#pragma unroll
            for (int sub = 0; sub < 4; ++sub) af[sub] = afn[sub];
        }
    }

    if (MODE == 0) {
        u16* outb = (u16*)outv;
#pragma unroll
        for (int sub = 0; sub < 4; ++sub) {
            int co4 = cg * 16 + sub * 4 + q;
#pragma unroll
            for (int t = 0; t < 7; ++t) {
                if (t < NT) {
                    int pxs = (t0 + t) * 16 + l15;
                    u16x4 o = {0, 0, 0, 0};
                    if (pxs < HW) {
#pragma unroll
                        for (int rg = 0; rg < 4; ++rg) {
                            int idx = (s * CCH + co4 * 4 + rg) * HW + pxs;
                            o[rg] = f2bf(acc[sub][t][rg] + xin[idx] + gcin[idx]);
                        }
                    }
                    if (pxs < 208)
                        *(u16x4*)(outb + (s * (size_t)SSTR) + (co4 * 208 + pxs) * 4) = o;
                }
            }
        }
    } else {
        float* outf = (float*)outv;
        float scl[4][4], mn[4][4], bt[4][4];
#pragma unroll
        for (int sub = 0; sub < 4; ++sub)
#pragma unroll
            for (int rg = 0; rg < 4; ++rg) {
                int c = cg * 64 + sub * 16 + q * 4 + rg;
                scl[sub][rg] = gamma[c] * rsqrtf(var[c] + 1e-5f);
                mn[sub][rg] = mean[c];
                bt[sub][rg] = beta[c];
            }
#pragma unroll
        for (int sub = 0; sub < 4; ++sub)
#pragma unroll
            for (int t = 0; t < 7; ++t) {
                if (t < NT) {
                    int pxs = (t0 + t) * 16 + l15;
                    if (pxs < HW) {
#pragma unroll
                        for (int rg = 0; rg < 4; ++rg) {
                            int co = cg * 64 + sub * 16 + q * 4 + rg;
                            float v = (acc[sub][t][rg] - mn[sub][rg]) * scl[sub][rg] + bt[sub][rg];
                            outf[(s * CCH + co) * HW + pxs] = fmaxf(v, 0.f);
                        }
                    }
                }
            }
    }
}

// ---------------- launch ----------------
extern "C" void kernel_launch(void* const* d_in, const int* in_sizes, int n_in,
                              void* d_out, int out_size, void* d_ws, size_t ws_size,
                              hipStream_t stream)
{
    const float* x    = (const float*)d_in[0];
    const float* gc   = (const float*)d_in[1];
    const float* boxes= (const float*)d_in[2];
    const int*   cls  = (const int*)d_in[3];
    const float* Wc3  = (const float*)d_in[4];
    const float* Wc1  = (const float*)d_in[5];
    const float* Wt3  = (const float*)d_in[6];
    const float* Wt1  = (const float*)d_in[7];
    const float* Wf3  = (const float*)d_in[8];
    const float* Wf1  = (const float*)d_in[9];
    const float* gam  = (const float*)d_in[10];
    const float* bet  = (const float*)d_in[11];
    const float* mea  = (const float*)d_in[12];
    const float* var  = (const float*)d_in[13];
    float* out = (float*)d_out;
    char* ws = (char*)d_ws;

    u16* w3      = (u16*)(ws);                 // 3,538,944 B
    u16* w1o     = (u16*)(ws + 3538944);       //   393,216 B
    int* counts  = (int*)(ws + 3932160);
    int* members = (int*)(ws + 3934208);       // 1 MB
    u16* bufA    = (u16*)(ws + 4982784);       // 54,525,952 B
    u16* bufB    = (u16*)(ws + 59508736);      // 54,525,952 B; end 114,034,688

    wconv_kernel<<<960, 256, 0, stream>>>(Wc3, Wt3, Wf3, Wc1, Wt1, Wf1, w3, w1o);
    mask_kernel<<<512, 64, 0, stream>>>(boxes, counts, members);
    bin_kernel<<<2048, 256, 0, stream>>>(x, cls, counts, members, bufA);
    conv3x3_kernel<<<2048, 256, 0, stream>>>(bufA, bufB, w3, w3 + 589824, cls, 1);
    conv1x1_kernel<0><<<512, 512, 0, stream>>>(bufB, w1o, w1o + 65536, cls, 1, x, gc,
                                               nullptr, nullptr, nullptr, nullptr, (void*)bufA);
    conv3x3_kernel<<<2048, 256, 0, stream>>>(bufA, bufB, w3 + 2 * 589824, w3, cls, 0);
    conv1x1_kernel<1><<<512, 512, 0, stream>>>(bufB, w1o + 2 * 65536, w1o, cls, 0, nullptr, nullptr,
                                               gam, bet, mea, var, (void*)out);
}

// Round 6
// 645.391 us; speedup vs baseline: 1.6345x; 1.6345x over previous
//
#include <hip/hip_runtime.h>

typedef unsigned short u16;
typedef unsigned int u32;
typedef __bf16 bf16x8 __attribute__((ext_vector_type(8)));
typedef float f32x4 __attribute__((ext_vector_type(4)));
typedef u16 u16x4 __attribute__((ext_vector_type(4)));
typedef u16 u16x8 __attribute__((ext_vector_type(8)));
typedef float f4v __attribute__((ext_vector_type(4)));

#define NB   512
#define CCH  256
#define HW   196
#define LROW 40                    // act LDS row stride (elems)
#define ACT_ELEMS (197 * LROW)     // 7880 elems per buffer (incl. halo row)
#define WLDS_ELEMS (9 * 64 * 32)   // 18432 elems
#define SSTR 53248                 // per-sample elems, blocked [c4][208][4]
#define CGSTR 147456               // w3 per-co-group stride: 8cc*9rs*64co*32ci

__device__ inline u16 f2bf(float f) {
    u32 u = __float_as_uint(f);
    u32 r = (u + 0x7FFFu + ((u >> 16) & 1u)) >> 16;
    return (u16)r;
}

// ---------------- weight convert / reorder ----------------
// 3x3: W[co][ci][r][s] f32 -> w3[set][cg][cc][rs][co64][ci32] bf16
__global__ void wconv_kernel(const float* __restrict__ Wc3, const float* __restrict__ Wt3,
                             const float* __restrict__ Wf3, const float* __restrict__ Wc1,
                             const float* __restrict__ Wt1, const float* __restrict__ Wf1,
                             u16* __restrict__ w3, u16* __restrict__ w1o)
{
    int bid = blockIdx.x, tid = threadIdx.x;
    if (bid < 768) {
        int wset = bid >> 8;
        int co = bid & 255;
        int cgi = co >> 6, cop = co & 63;
        int cc = tid >> 5, cip = tid & 31;
        const float* src = wset == 0 ? Wc3 : (wset == 1 ? Wt3 : Wf3);
#pragma unroll
        for (int rs = 0; rs < 9; ++rs) {
            float v = src[(co * 256 + tid) * 9 + rs];
            w3[wset * 589824 + cgi * CGSTR + (cc * 9 + rs) * 2048 + cop * 32 + cip] = f2bf(v);
        }
    } else {
        int k = (bid - 768) * 256 + tid;
        int wsel = k >> 14;
        int rem = k & 16383;
        const float* src = wsel == 0 ? Wc1 : (wsel == 1 ? Wt1 : Wf1);
        f4v v = *(const f4v*)(src + rem * 4);
        u16x4 o = { f2bf(v.x), f2bf(v.y), f2bf(v.z), f2bf(v.w) };
        *(u16x4*)(w1o + wsel * 65536 + rem * 4) = o;
    }
}

// ---------------- box overlap mask ----------------
__global__ void mask_kernel(const float* __restrict__ boxes, int* __restrict__ counts,
                            int* __restrict__ members)
{
    int i = blockIdx.x;
    int ln = threadIdx.x;
    __shared__ int cnt;
    if (ln == 0) cnt = 0;
    __syncthreads();
    float xi0 = boxes[i * 4 + 0], yi0 = boxes[i * 4 + 1];
    float xi1 = boxes[i * 4 + 2], yi1 = boxes[i * 4 + 3];
    for (int j = ln; j < NB; j += 64) {
        float xj0 = boxes[j * 4 + 0], yj0 = boxes[j * 4 + 1];
        float xj1 = boxes[j * 4 + 2], yj1 = boxes[j * 4 + 3];
        float areaj = (xj1 - xj0) * (yj1 - yj0);
        float lx = fmaxf(xi0, xj0), ly = fmaxf(yi0, yj0);
        float rx = fminf(xi1, xj1), ry = fminf(yi1, yj1);
        float w = fmaxf(rx - lx, 0.f), h = fmaxf(ry - ly, 0.f);
        if (w * h / areaj > 0.9f) {
            int p = atomicAdd(&cnt, 1);
            members[i * NB + p] = j;
        }
    }
    __syncthreads();
    if (ln == 0) counts[i] = cnt;
}

// ---------------- branch input -> blocked bf16 [s][c4][208][4] ----------------
__global__ __launch_bounds__(256) void bin_kernel(
    const float* __restrict__ x, const int* __restrict__ classes,
    const int* __restrict__ counts, const int* __restrict__ members,
    u16* __restrict__ bin)
{
    const int bid = blockIdx.x;
    const int s = bid >> 2;
    const int qtr = bid & 3;
    const int tid = threadIdx.x;
    const int cnt = counts[s];
    u16* binS = bin + s * SSTR;
    __shared__ int mem[NB];
    int lcnt;
    if (classes[s] != 0 || cnt <= 1) {
        if (tid == 0) mem[0] = s;
        lcnt = 1;
    } else {
        for (int u = tid; u < cnt; u += 256) mem[u] = members[s * NB + u];
        lcnt = cnt;
    }
    __syncthreads();
    const float inv = 1.f / (float)lcnt;
    for (int v = tid; v < 784; v += 256) {
        int c4r = v / 49;
        int g = v - c4r * 49;
        int c4 = qtr * 16 + c4r;
        int px0 = g * 4;
        f4v a0 = {0.f, 0.f, 0.f, 0.f}, a1 = a0, a2 = a0, a3 = a0;
        for (int k = 0; k < lcnt; ++k) {
            const float* xm = x + (size_t)(mem[k] * CCH + c4 * 4) * HW + px0;
            a0 += *(const f4v*)(xm);
            a1 += *(const f4v*)(xm + HW);
            a2 += *(const f4v*)(xm + 2 * HW);
            a3 += *(const f4v*)(xm + 3 * HW);
        }
        u16x8 o0, o1;
        o0[0] = f2bf(a0.x * inv); o0[1] = f2bf(a1.x * inv);
        o0[2] = f2bf(a2.x * inv); o0[3] = f2bf(a3.x * inv);
        o0[4] = f2bf(a0.y * inv); o0[5] = f2bf(a1.y * inv);
        o0[6] = f2bf(a2.y * inv); o0[7] = f2bf(a3.y * inv);
        o1[0] = f2bf(a0.z * inv); o1[1] = f2bf(a1.z * inv);
        o1[2] = f2bf(a2.z * inv); o1[3] = f2bf(a3.z * inv);
        o1[4] = f2bf(a0.w * inv); o1[5] = f2bf(a1.w * inv);
        o1[6] = f2bf(a2.w * inv); o1[7] = f2bf(a3.w * inv);
        u16* dst = binS + (c4 * 208 + px0) * 4;
        *(u16x8*)(dst) = o0;
        *(u16x8*)(dst + 8) = o1;
    }
}

// ---------------- conv3x3: exact R1 structure (159 us known-good) ----------------
// LDS-staged weights + acts, 2 barriers/cc, 64co x 13t per block, 3 blocks/CU.
__global__ __launch_bounds__(256, 3) void conv3x3_kernel(
    const u16* __restrict__ in, u16* __restrict__ out,
    const u16* __restrict__ w0, const u16* __restrict__ w1,
    const int* __restrict__ classes, int useClass)
{
    __shared__ u16 lds[ACT_ELEMS + WLDS_ELEMS];   // 52,624 B -> 3 blocks/CU
    const int tid = threadIdx.x;
    const int bid = blockIdx.x;
    const int s  = bid >> 2;
    const int cg = bid & 3;
    const int wv = tid >> 6;
    const int ln = tid & 63;
    const int q = ln >> 4;
    const int l15 = ln & 15;
    const int t0 = (wv == 0) ? 0 : (wv == 1 ? 4 : (wv == 2 ? 7 : 10));
    const int NT = (wv == 0) ? 4 : 3;

    const u16* wsel = (((useClass && classes[s] == 0) ? w1 : w0)) + cg * CGSTR;

    if (tid < 20) ((u32*)lds)[196 * (LROW / 2) + tid] = 0u;   // zero halo row

    int baddr[4], vbits[4];
#pragma unroll
    for (int t = 0; t < 4; ++t) {
        int px = (t0 + t) * 16 + l15;
        int vb = 0;
        int ba = 196 * LROW + q * 8;
        if (t < NT && px < HW) {
            int y = px / 14;
            int x = px - y * 14;
            ba = px * LROW + q * 8;
#pragma unroll
            for (int rs = 0; rs < 9; ++rs) {
                int iy = y + rs / 3 - 1;
                int ix = x + rs % 3 - 1;
                if (iy >= 0 && iy < 14 && ix >= 0 && ix < 14) vb |= 1 << rs;
            }
        }
        baddr[t] = ba;
        vbits[t] = vb;
    }

    f32x4 acc[4][4];
#pragma unroll
    for (int a = 0; a < 4; ++a)
#pragma unroll
        for (int t = 0; t < 4; ++t) acc[a][t] = (f32x4){0.f, 0.f, 0.f, 0.f};

    const u16* inS = in + s * SSTR;

    for (int cc = 0; cc < 8; ++cc) {
        __syncthreads();
        // stage activations: 32 ci x 196 px, transposed to [px][ci32]
        for (int v = tid; v < 1568; v += 256) {
            int ci4 = v & 7;
            int px = v >> 3;
            u16x4 val = *(const u16x4*)(inS + ((cc * 8 + ci4) * 208 + px) * 4);
            *(u16x4*)(lds + px * LROW + ci4 * 4) = val;
        }
        // stage weights: 9rs x 64co x 32ci contiguous b128 copy
        {
            const u16* wcc = wsel + cc * WLDS_ELEMS;
#pragma unroll
            for (int k = 0; k < 9; ++k) {
                int idx = tid + k * 256;
                *(u16x8*)(lds + ACT_ELEMS + idx * 8) = *(const u16x8*)(wcc + idx * 8);
            }
        }
        __syncthreads();

#pragma unroll
        for (int rs = 0; rs < 9; ++rs) {
            const int d = (rs / 3 - 1) * 14 + (rs % 3 - 1);
            bf16x8 af[4];
#pragma unroll
            for (int sub = 0; sub < 4; ++sub)
                af[sub] = *(const bf16x8*)(lds + ACT_ELEMS + rs * 2048 + (sub * 16 + l15) * 32 + q * 8);
#pragma unroll
            for (int t = 0; t < 4; ++t) {
                if (t < NT) {
                    int addr = ((vbits[t] >> rs) & 1) ? (baddr[t] + d * LROW)
                                                      : (196 * LROW + q * 8);
                    bf16x8 b = *(const bf16x8*)(lds + addr);
#pragma unroll
                    for (int sub = 0; sub < 4; ++sub)
                        acc[sub][t] = __builtin_amdgcn_mfma_f32_16x16x32_bf16(af[sub], b, acc[sub][t], 0, 0, 0);
                }
            }
        }
    }

#pragma unroll
    for (int sub = 0; sub < 4; ++sub) {
        int co4 = cg * 16 + sub * 4 + q;
#pragma unroll
        for (int t = 0; t < 4; ++t) {
            if (t < NT) {
                int pxs = (t0 + t) * 16 + l15;
                u16x4 o = { f2bf(acc[sub][t][0]), f2bf(acc[sub][t][1]),
                            f2bf(acc[sub][t][2]), f2bf(acc[sub][t][3]) };
                *(u16x4*)(out + (s * (size_t)SSTR) + (co4 * 208 + pxs) * 4) = o;
            }
        }
    }
}

// ---------------- conv1x1 v3: merged-sample (512 thr, 8 waves = 4cg x 2 px-halves)
// Acts staged ONCE per sample (was 4x), double-buffered, ONE barrier per cc,
// act+weight reg-prefetch. Weights from global (L1/L2-resident). KEPT from R5
// (saved ~120 us total vs R1's conv1x1).
template <int MODE>
__global__ __launch_bounds__(512) void conv1x1_kernel(
    const u16* __restrict__ in, const u16* __restrict__ w0, const u16* __restrict__ w1,
    const int* __restrict__ classes, int useClass,
    const float* __restrict__ xin, const float* __restrict__ gcin,
    const float* __restrict__ gamma, const float* __restrict__ beta,
    const float* __restrict__ mean, const float* __restrict__ var,
    void* __restrict__ outv)
{
    __shared__ u16 lds[2 * ACT_ELEMS];            // 31,520 B
    const int tid = threadIdx.x;
    const int s  = blockIdx.x;
    const int wv = tid >> 6;                      // 0..7
    const int ln = tid & 63;
    const int q = ln >> 4;
    const int l15 = ln & 15;
    const int cg  = wv >> 1;
    const int pxh = wv & 1;
    const int t0 = pxh ? 7 : 0;
    const int NT = pxh ? 6 : 7;

    const u16* wsel = (useClass && classes[s] == 0) ? w1 : w0;

    if (tid < 20) {
        ((u32*)lds)[196 * (LROW / 2) + tid] = 0u;
        ((u32*)lds)[(ACT_ELEMS / 2) + 196 * (LROW / 2) + tid] = 0u;
    }

    int baddr[7];
#pragma unroll
    for (int t = 0; t < 7; ++t) {
        int px = (t0 + t) * 16 + l15;
        baddr[t] = (t < NT && px < HW ? px : 196) * LROW + q * 8;
    }

    f32x4 acc[4][7];
#pragma unroll
    for (int a = 0; a < 4; ++a)
#pragma unroll
        for (int t = 0; t < 7; ++t) acc[a][t] = (f32x4){0.f, 0.f, 0.f, 0.f};

    const u16* inS = in + s * (size_t)SSTR;

    // staging items, px-major (coalesced): v = ci4*196 + px, 1568 = 3*512 + 32
    int goff[4], loff[4];
#pragma unroll
    for (int j = 0; j < 4; ++j) {
        int v = tid + j * 512;
        if (v > 1567) v = 1567;
        int ci4 = v / 196;
        int px = v - ci4 * 196;
        goff[j] = (ci4 * 208 + px) * 4;
        loff[j] = px * LROW + ci4 * 4;
    }
    const int has4 = (tid < 32);

    u16x4 apf[4];
    bf16x8 af[4];
    // prologue: stage cc=0 into buf0, load af(cc=0)
    {
#pragma unroll
        for (int j = 0; j < 3; ++j) apf[j] = *(const u16x4*)(inS + goff[j]);
        if (has4) apf[3] = *(const u16x4*)(inS + goff[3]);
#pragma unroll
        for (int j = 0; j < 3; ++j) *(u16x4*)(lds + loff[j]) = apf[j];
        if (has4) *(u16x4*)(lds + loff[3]) = apf[3];
#pragma unroll
        for (int sub = 0; sub < 4; ++sub)
            af[sub] = *(const bf16x8*)(wsel + ((cg * 64 + sub * 16 + l15) * 256 + q * 8));
    }

    for (int cc = 0; cc < 8; ++cc) {
        __syncthreads();   // buf[cc&1] staged; compute(cc-1) done
        // issue next-cc loads (acts + weights) -> regs
        bf16x8 afn[4];
        if (cc < 7) {
            const u16* gs = inS + (cc + 1) * (8 * 208 * 4);
#pragma unroll
            for (int j = 0; j < 3; ++j) apf[j] = *(const u16x4*)(gs + goff[j]);
            if (has4) apf[3] = *(const u16x4*)(gs + goff[3]);
#pragma unroll
            for (int sub = 0; sub < 4; ++sub)
                afn[sub] = *(const bf16x8*)(wsel + ((cg * 64 + sub * 16 + l15) * 256 + (cc + 1) * 32 + q * 8));
        }
        const u16* bb = lds + (cc & 1) * ACT_ELEMS;
#pragma unroll
        for (int t = 0; t < 7; ++t) {
            if (t < NT) {
                bf16x8 b = *(const bf16x8*)(bb + baddr[t]);
#pragma unroll
                for (int sub = 0; sub < 4; ++sub)
                    acc[sub][t] = __builtin_amdgcn_mfma_f32_16x16x32_bf16(af[sub], b, acc[sub][t], 0, 0, 0);
            }
        }
        if (cc < 7) {
            u16* nb = lds + ((cc + 1) & 1) * ACT_ELEMS;
#pragma unroll
            for (int j = 0; j < 3; ++j) *(u16x4*)(nb + loff[j]) = apf[j];
            if (has4) *(u16x4*)(nb + loff[3]) = apf[3];
#pragma unroll
            for (int sub = 0; sub < 4; ++sub) af[sub] = afn[sub];
        }
    }

    if (MODE == 0) {
        u16* outb = (u16*)outv;
#pragma unroll
        for (int sub = 0; sub < 4; ++sub) {
            int co4 = cg * 16 + sub * 4 + q;
#pragma unroll
            for (int t = 0; t < 7; ++t) {
                if (t < NT) {
                    int pxs = (t0 + t) * 16 + l15;
                    u16x4 o = {0, 0, 0, 0};
                    if (pxs < HW) {
#pragma unroll
                        for (int rg = 0; rg < 4; ++rg) {
                            int idx = (s * CCH + co4 * 4 + rg) * HW + pxs;
                            o[rg] = f2bf(acc[sub][t][rg] + xin[idx] + gcin[idx]);
                        }
                    }
                    if (pxs < 208)
                        *(u16x4*)(outb + (s * (size_t)SSTR) + (co4 * 208 + pxs) * 4) = o;
                }
            }
        }
    } else {
        float* outf = (float*)outv;
        float scl[4][4], mn[4][4], bt[4][4];
#pragma unroll
        for (int sub = 0; sub < 4; ++sub)
#pragma unroll
            for (int rg = 0; rg < 4; ++rg) {
                int c = cg * 64 + sub * 16 + q * 4 + rg;
                scl[sub][rg] = gamma[c] * rsqrtf(var[c] + 1e-5f);
                mn[sub][rg] = mean[c];
                bt[sub][rg] = beta[c];
            }
#pragma unroll
        for (int sub = 0; sub < 4; ++sub)
#pragma unroll
            for (int t = 0; t < 7; ++t) {
                if (t < NT) {
                    int pxs = (t0 + t) * 16 + l15;
                    if (pxs < HW) {
#pragma unroll
                        for (int rg = 0; rg < 4; ++rg) {
                            int co = cg * 64 + sub * 16 + q * 4 + rg;
                            float v = (acc[sub][t][rg] - mn[sub][rg]) * scl[sub][rg] + bt[sub][rg];
                            outf[(s * CCH + co) * HW + pxs] = fmaxf(v, 0.f);
                        }
                    }
                }
            }
    }
}

// ---------------- launch ----------------
extern "C" void kernel_launch(void* const* d_in, const int* in_sizes, int n_in,
                              void* d_out, int out_size, void* d_ws, size_t ws_size,
                              hipStream_t stream)
{
    const float* x    = (const float*)d_in[0];
    const float* gc   = (const float*)d_in[1];
    const float* boxes= (const float*)d_in[2];
    const int*   cls  = (const int*)d_in[3];
    const float* Wc3  = (const float*)d_in[4];
    const float* Wc1  = (const float*)d_in[5];
    const float* Wt3  = (const float*)d_in[6];
    const float* Wt1  = (const float*)d_in[7];
    const float* Wf3  = (const float*)d_in[8];
    const float* Wf1  = (const float*)d_in[9];
    const float* gam  = (const float*)d_in[10];
    const float* bet  = (const float*)d_in[11];
    const float* mea  = (const float*)d_in[12];
    const float* var  = (const float*)d_in[13];
    float* out = (float*)d_out;
    char* ws = (char*)d_ws;

    u16* w3      = (u16*)(ws);                 // 3,538,944 B
    u16* w1o     = (u16*)(ws + 3538944);       //   393,216 B
    int* counts  = (int*)(ws + 3932160);
    int* members = (int*)(ws + 3934208);       // 1 MB
    u16* bufA    = (u16*)(ws + 4982784);       // 54,525,952 B
    u16* bufB    = (u16*)(ws + 59508736);      // 54,525,952 B; end 114,034,688

    wconv_kernel<<<960, 256, 0, stream>>>(Wc3, Wt3, Wf3, Wc1, Wt1, Wf1, w3, w1o);
    mask_kernel<<<512, 64, 0, stream>>>(boxes, counts, members);
    bin_kernel<<<2048, 256, 0, stream>>>(x, cls, counts, members, bufA);
    conv3x3_kernel<<<2048, 256, 0, stream>>>(bufA, bufB, w3, w3 + 589824, cls, 1);
    conv1x1_kernel<0><<<512, 512, 0, stream>>>(bufB, w1o, w1o + 65536, cls, 1, x, gc,
                                               nullptr, nullptr, nullptr, nullptr, (void*)bufA);
    conv3x3_kernel<<<2048, 256, 0, stream>>>(bufA, bufB, w3 + 2 * 589824, w3, cls, 0);
    conv1x1_kernel<1><<<512, 512, 0, stream>>>(bufB, w1o + 2 * 65536, w1o, cls, 0, nullptr, nullptr,
                                               gam, bet, mea, var, (void*)out);
}